// Round 9
// baseline (309.987 us; speedup 1.0000x reference)
//
#include <hip/hip_runtime.h>
#include <hip/hip_bf16.h>

#define NN 1024
#define IN_CH 128
#define EDGE_CH 32
#define OUT_CH 128
#define NNSQ ((size_t)NN * (size_t)NN)

typedef __attribute__((ext_vector_type(8))) short bf16x8;
typedef __attribute__((ext_vector_type(4))) float f32x4;
typedef __attribute__((ext_vector_type(2))) float f32x2;

// round-to-nearest-even float -> bf16 (bit trick)
static __device__ __forceinline__ short f2bf(float f) {
    union { float f; unsigned u; } v; v.f = f;
    unsigned r = v.u + 0x7FFFu + ((v.u >> 16) & 1u);
    return (short)(r >> 16);
}

// ---------------------------------------------------------------------------
// Kernel A: P = node_mat @ node_weight (stored TRANSPOSED, bf16: PT[o][m]),
//           R = node_mat @ root (fp32).  (unchanged)
// ---------------------------------------------------------------------------
__global__ void node_gemm_kernel(const float* __restrict__ node_mat,
                                 const float* __restrict__ node_weight,
                                 const float* __restrict__ root,
                                 short* __restrict__ PT,
                                 float* __restrict__ R) {
    __shared__ float nm[2 * IN_CH];
    int tid = threadIdx.x;
    int n0 = blockIdx.x * 2;
    nm[tid] = node_mat[n0 * IN_CH + tid];
    __syncthreads();
    int o = tid & 127;
    int h = tid >> 7;
    const float* nr = &nm[h * IN_CH];
    float accp = 0.f, accr = 0.f;
#pragma unroll 8
    for (int c = 0; c < IN_CH; ++c) {
        float x = nr[c];
        accp += x * node_weight[c * OUT_CH + o];
        accr += x * root[c * OUT_CH + o];
    }
    R[(size_t)(n0 + h) * OUT_CH + o] = accr;
    PT[(size_t)o * NN + (n0 + h)] = f2bf(accp);  // transposed bf16 store
}

// ---------------------------------------------------------------------------
// Kernel C (runs before edge_out): out = adj @ P + R + bias  (WRITE mode).
// (unchanged)
// ---------------------------------------------------------------------------
__global__ void adjp_kernel(const float* __restrict__ adj,
                            const short* __restrict__ PT,
                            const float* __restrict__ R,
                            const float* __restrict__ bias,
                            float* __restrict__ out) {
    int blk = blockIdx.x;
    int nb = blk & 63;          // n-tile: 16 rows
    int oh = blk >> 6;          // o-half: 64 cols
    int tid = threadIdx.x;
    int wave = tid >> 6;
    int lane = tid & 63;
    int quad = lane >> 4;
    int col  = lane & 15;
    int n0 = nb * 16;
    int o0 = oh * 64;

    f32x4 acc[4];
#pragma unroll
    for (int ot = 0; ot < 4; ++ot) acc[ot] = (f32x4){0.f, 0.f, 0.f, 0.f};

    int kbase = wave * 256;     // wave-level K-split, reduced in LDS below
#pragma unroll
    for (int ks = 0; ks < 8; ++ks) {
        int k = kbase + ks * 32 + quad * 8;
        const float* ap = adj + (size_t)(n0 + col) * NN + k;
        f32x4 a0 = *(const f32x4*)ap;
        f32x4 a1 = *(const f32x4*)(ap + 4);
        bf16x8 a;
#pragma unroll
        for (int j = 0; j < 4; ++j) { a[j] = f2bf(a0[j]); a[4 + j] = f2bf(a1[j]); }
#pragma unroll
        for (int ot = 0; ot < 4; ++ot) {
            int o = o0 + ot * 16 + col;
            bf16x8 b = *(const bf16x8*)(PT + (size_t)o * NN + k);
            acc[ot] = __builtin_amdgcn_mfma_f32_16x16x32_bf16(a, b, acc[ot], 0, 0, 0);
        }
    }

    __shared__ float red[4][16][65];
#pragma unroll
    for (int ot = 0; ot < 4; ++ot)
#pragma unroll
        for (int r = 0; r < 4; ++r)
            red[wave][quad * 4 + r][ot * 16 + col] = acc[ot][r];
    __syncthreads();

#pragma unroll
    for (int i = tid; i < 16 * 64; i += 256) {
        int rr = i >> 6;
        int cc = i & 63;
        float v = red[0][rr][cc] + red[1][rr][cc] + red[2][rr][cc] + red[3][rr][cc];
        size_t idx = (size_t)(n0 + rr) * OUT_CH + o0 + cc;
        out[idx] = v + R[idx] + bias[o0 + cc];
    }
}

// ---------------------------------------------------------------------------
// Kernel B v8 (heavy): per (n, half), partial over m in [half*512, +512):
//   Gp[b] = sum_m adj[n,m] * relu( sum_e edge_adj[e,n,m] * L1[e,b] )
//   atomicAdd(out[n,o], sum_{b<127} Gp[b]*L2[b,o])   (base pre-written by adjp)
//
// v7 post-mortem: nt loads real but small (+10 us); gather still capped
// ~1.9 TB/s. Series evidence: throughput tracks CONCURRENCY BREADTH
// (v2 lockstep 1.0 -> v6 2-deep 1.7 TB/s), and every variant was pinned at
// 3-4 blocks/CU by grid=1024 + 46.6 KB LDS. v8 raises resident streams
// 1.5-2x with one structural change:
//   - n split into 2 m-halves: grid 2048 (atomic epilogue, v4-proven)
//   - chunk = 128 m -> LDS ~24 KB -> 6 blocks/CU (24 waves/CU)
//   - __launch_bounds__(256,6) (VGPR budget ~340 -> no spill at ~75)
//   - 2-deep named-bank prefetch + nt loads kept; f32x2 staging (8 B/lane)
// Geometry else unchanged: b-split across waves (wave owns b-tiles
// {2w,2w+1}); LDS transposed [m][40 shorts]; chunk rotation for channel
// spread. MFMA 16x16x32: A=L1^T const frags; B = ds_read_b128 [m][e];
// D row=quad*4+r (b), col=m.
// ---------------------------------------------------------------------------
__global__ void __launch_bounds__(256, 6)
edge_out_kernel(const float* __restrict__ edge_adj,
                const float* __restrict__ adj,
                const float* __restrict__ L1,
                const float* __restrict__ L2,
                float* __restrict__ out) {
    int n    = blockIdx.x >> 1;
    int half = blockIdx.x & 1;
    int tid = threadIdx.x;
    int wave = tid >> 6;
    int lane = tid & 63;
    int quad = lane >> 4;
    int col  = lane & 15;

    // double-buffered transposed chunk: [128 m][40 shorts] = 10 KB each
    __shared__ __attribute__((aligned(16))) short ea_lds[2][128 * 40];  // 20 KB
    __shared__ float adj_lds[512];                                      // 2 KB
    __shared__ float gs[OUT_CH];
    __shared__ float part[2][OUT_CH];

    int mbase = half * 512;
    // stage this half's adj row (coalesced, 2 KB)
    if (tid < 128)
        *(f32x4*)&adj_lds[tid * 4] = *(const f32x4*)(adj + (size_t)n * NN + mbase + tid * 4);

    // A fragments: this wave's two b-tiles of L1^T [b][e=quad*8+j]
    bf16x8 a_frag0, a_frag1;
#pragma unroll
    for (int j = 0; j < 8; ++j) {
        int e = quad * 8 + j;
        int b0 = (wave * 2 + 0) * 16 + col;
        int b1 = (wave * 2 + 1) * 16 + col;
        a_frag0[j] = f2bf((b0 < OUT_CH - 1) ? L1[e * (OUT_CH - 1) + b0] : 0.0f);
        a_frag1[j] = f2bf((b1 < OUT_CH - 1) ? L1[e * (OUT_CH - 1) + b1] : 0.0f);
    }

    float g0[4] = {0.f, 0.f, 0.f, 0.f};
    float g1[4] = {0.f, 0.f, 0.f, 0.f};

    // staging base: this wave's 8 e-planes, this n's row-half, lane covers 2 m
    const float* ea_b = edge_adj + (size_t)(wave * 8) * NNSQ + (size_t)n * NN
                        + mbase + lane * 2;

    f32x2 stA0, stA1, stA2, stA3, stA4, stA5, stA6, stA7;   // bank A
    f32x2 stB0, stB1, stB2, stB3, stB4, stB5, stB6, stB7;   // bank B

#define NTLD(P) __builtin_nontemporal_load((const f32x2*)(P))
#define ISSUE_A(AC) { \
        const float* p_ = ea_b + (AC) * 128; \
        stA0 = NTLD(p_ + 0 * NNSQ); stA1 = NTLD(p_ + 1 * NNSQ); \
        stA2 = NTLD(p_ + 2 * NNSQ); stA3 = NTLD(p_ + 3 * NNSQ); \
        stA4 = NTLD(p_ + 4 * NNSQ); stA5 = NTLD(p_ + 5 * NNSQ); \
        stA6 = NTLD(p_ + 6 * NNSQ); stA7 = NTLD(p_ + 7 * NNSQ); }
#define ISSUE_B(AC) { \
        const float* p_ = ea_b + (AC) * 128; \
        stB0 = NTLD(p_ + 0 * NNSQ); stB1 = NTLD(p_ + 1 * NNSQ); \
        stB2 = NTLD(p_ + 2 * NNSQ); stB3 = NTLD(p_ + 3 * NNSQ); \
        stB4 = NTLD(p_ + 4 * NNSQ); stB5 = NTLD(p_ + 5 * NNSQ); \
        stB6 = NTLD(p_ + 6 * NNSQ); stB7 = NTLD(p_ + 7 * NNSQ); }
// lane holds 8e x 2m; write 2 rows of 8 bf16 (16 B) = 2x ds_write_b128
#define CONVERT_A(BUF) { \
        _Pragma("unroll") for (int k = 0; k < 2; ++k) { \
            bf16x8 pk_; \
            pk_[0] = f2bf(stA0[k]); pk_[1] = f2bf(stA1[k]); \
            pk_[2] = f2bf(stA2[k]); pk_[3] = f2bf(stA3[k]); \
            pk_[4] = f2bf(stA4[k]); pk_[5] = f2bf(stA5[k]); \
            pk_[6] = f2bf(stA6[k]); pk_[7] = f2bf(stA7[k]); \
            *(bf16x8*)((BUF) + (lane * 2 + k) * 40 + wave * 8) = pk_; } }
#define CONVERT_B(BUF) { \
        _Pragma("unroll") for (int k = 0; k < 2; ++k) { \
            bf16x8 pk_; \
            pk_[0] = f2bf(stB0[k]); pk_[1] = f2bf(stB1[k]); \
            pk_[2] = f2bf(stB2[k]); pk_[3] = f2bf(stB3[k]); \
            pk_[4] = f2bf(stB4[k]); pk_[5] = f2bf(stB5[k]); \
            pk_[6] = f2bf(stB6[k]); pk_[7] = f2bf(stB7[k]); \
            *(bf16x8*)((BUF) + (lane * 2 + k) * 40 + wave * 8) = pk_; } }
#define COMPUTE(BUF, AC) { \
        _Pragma("unroll") for (int st = 0; st < 8; ++st) { \
            int mrow = st * 16 + col; \
            float adjv = adj_lds[(AC) * 128 + mrow]; \
            bf16x8 bfv = *(const bf16x8*)((BUF) + mrow * 40 + quad * 8); \
            f32x4 d0 = __builtin_amdgcn_mfma_f32_16x16x32_bf16( \
                a_frag0, bfv, (f32x4){0.f, 0.f, 0.f, 0.f}, 0, 0, 0); \
            f32x4 d1 = __builtin_amdgcn_mfma_f32_16x16x32_bf16( \
                a_frag1, bfv, (f32x4){0.f, 0.f, 0.f, 0.f}, 0, 0, 0); \
            _Pragma("unroll") for (int r = 0; r < 4; ++r) { \
                g0[r] += fmaxf(d0[r], 0.0f) * adjv; \
                g1[r] += fmaxf(d1[r], 0.0f) * adjv; } } }

    const int base = (n + half) & 3;
    const int c0 = base, c1 = (base + 1) & 3, c2 = (base + 2) & 3, c3 = (base + 3) & 3;
    short* buf0 = &ea_lds[0][0];
    short* buf1 = &ea_lds[1][0];

    // fully-unrolled 2-deep schedule (all register indices static)
    ISSUE_A(c0); ISSUE_B(c1);
    CONVERT_A(buf0);
    __syncthreads();

    ISSUE_A(c2);
    COMPUTE(buf0, c0);
    CONVERT_B(buf1);
    __syncthreads();

    ISSUE_B(c3);
    COMPUTE(buf1, c1);
    CONVERT_A(buf0);
    __syncthreads();

    COMPUTE(buf0, c2);
    CONVERT_B(buf1);
    __syncthreads();

    COMPUTE(buf1, c3);

#undef NTLD
#undef ISSUE_A
#undef ISSUE_B
#undef CONVERT_A
#undef CONVERT_B
#undef COMPUTE

    // reduce over the 16 column-lanes (sum over m within subtile columns)
#pragma unroll
    for (int r = 0; r < 4; ++r) {
        float v0 = g0[r], v1 = g1[r];
        v0 += __shfl_xor(v0, 1); v1 += __shfl_xor(v1, 1);
        v0 += __shfl_xor(v0, 2); v1 += __shfl_xor(v1, 2);
        v0 += __shfl_xor(v0, 4); v1 += __shfl_xor(v1, 4);
        v0 += __shfl_xor(v0, 8); v1 += __shfl_xor(v1, 8);
        g0[r] = v0; g1[r] = v1;
    }

    // each b owned by exactly one wave -> write gs directly
    if (col == 0) {
#pragma unroll
        for (int r = 0; r < 4; ++r) {
            gs[(wave * 2 + 0) * 16 + quad * 4 + r] = g0[r];
            gs[(wave * 2 + 1) * 16 + quad * 4 + r] = g1[r];
        }
    }
    __syncthreads();

    // partial epilogue: atomicAdd(out[n,o], sum_{b<127} gs[b]*L2[b,o])
    int o = tid & 127;
    int hf = tid >> 7;
    float acc = 0.f;
    int blo = hf * 64, bhi = hf ? 127 : 64;
#pragma unroll 8
    for (int b = blo; b < bhi; ++b)
        acc += gs[b] * L2[b * OUT_CH + o];   // gs[b] is an LDS broadcast (free)
    part[hf][o] = acc;
    __syncthreads();
    if (tid < 128)
        atomicAdd(&out[(size_t)n * OUT_CH + tid], part[0][tid] + part[1][tid]);
}

extern "C" void kernel_launch(void* const* d_in, const int* in_sizes, int n_in,
                              void* d_out, int out_size, void* d_ws, size_t ws_size,
                              hipStream_t stream) {
    const float* node_mat    = (const float*)d_in[0];
    const float* adj         = (const float*)d_in[1];
    const float* edge_adj    = (const float*)d_in[2];
    const float* node_weight = (const float*)d_in[3];
    const float* edge_lay_1  = (const float*)d_in[4];
    const float* edge_lay_2  = (const float*)d_in[5];
    const float* root        = (const float*)d_in[6];
    const float* bias        = (const float*)d_in[7];
    float* out = (float*)d_out;

    short* PT = (short*)d_ws;                       // 128*1024 bf16 = 256 KB
    float* R  = (float*)((char*)d_ws + OUT_CH * NN * sizeof(short));  // 512 KB

    node_gemm_kernel<<<NN / 2, 256, 0, stream>>>(node_mat, node_weight, root, PT, R);
    adjp_kernel<<<128, 256, 0, stream>>>(adj, PT, R, bias, out);   // writes base
    edge_out_kernel<<<2 * NN, 256, 0, stream>>>(edge_adj, adj, edge_lay_1,
                                                edge_lay_2, out);  // atomic +=
}

// Round 10
// 249.040 us; speedup vs baseline: 1.2447x; 1.2447x over previous
//
#include <hip/hip_runtime.h>
#include <hip/hip_bf16.h>

#define NN 1024
#define IN_CH 128
#define EDGE_CH 32
#define OUT_CH 128
#define NNSQ ((size_t)NN * (size_t)NN)

typedef __attribute__((ext_vector_type(8))) short bf16x8;
typedef __attribute__((ext_vector_type(4))) float f32x4;
typedef __attribute__((ext_vector_type(2))) float f32x2;

// round-to-nearest-even float -> bf16 (bit trick)
static __device__ __forceinline__ short f2bf(float f) {
    union { float f; unsigned u; } v; v.f = f;
    unsigned r = v.u + 0x7FFFu + ((v.u >> 16) & 1u);
    return (short)(r >> 16);
}

// ---------------------------------------------------------------------------
// Kernel A: P = node_mat @ node_weight (stored TRANSPOSED, bf16: PT[o][m]),
//           R = node_mat @ root (fp32).  (unchanged)
// ---------------------------------------------------------------------------
__global__ void node_gemm_kernel(const float* __restrict__ node_mat,
                                 const float* __restrict__ node_weight,
                                 const float* __restrict__ root,
                                 short* __restrict__ PT,
                                 float* __restrict__ R) {
    __shared__ float nm[2 * IN_CH];
    int tid = threadIdx.x;
    int n0 = blockIdx.x * 2;
    nm[tid] = node_mat[n0 * IN_CH + tid];
    __syncthreads();
    int o = tid & 127;
    int h = tid >> 7;
    const float* nr = &nm[h * IN_CH];
    float accp = 0.f, accr = 0.f;
#pragma unroll 8
    for (int c = 0; c < IN_CH; ++c) {
        float x = nr[c];
        accp += x * node_weight[c * OUT_CH + o];
        accr += x * root[c * OUT_CH + o];
    }
    R[(size_t)(n0 + h) * OUT_CH + o] = accr;
    PT[(size_t)o * NN + (n0 + h)] = f2bf(accp);  // transposed bf16 store
}

// ---------------------------------------------------------------------------
// Kernel C (runs before edge_out): out = adj @ P + R + bias  (WRITE mode).
// (unchanged)
// ---------------------------------------------------------------------------
__global__ void adjp_kernel(const float* __restrict__ adj,
                            const short* __restrict__ PT,
                            const float* __restrict__ R,
                            const float* __restrict__ bias,
                            float* __restrict__ out) {
    int blk = blockIdx.x;
    int nb = blk & 63;          // n-tile: 16 rows
    int oh = blk >> 6;          // o-half: 64 cols
    int tid = threadIdx.x;
    int wave = tid >> 6;
    int lane = tid & 63;
    int quad = lane >> 4;
    int col  = lane & 15;
    int n0 = nb * 16;
    int o0 = oh * 64;

    f32x4 acc[4];
#pragma unroll
    for (int ot = 0; ot < 4; ++ot) acc[ot] = (f32x4){0.f, 0.f, 0.f, 0.f};

    int kbase = wave * 256;     // wave-level K-split, reduced in LDS below
#pragma unroll
    for (int ks = 0; ks < 8; ++ks) {
        int k = kbase + ks * 32 + quad * 8;
        const float* ap = adj + (size_t)(n0 + col) * NN + k;
        f32x4 a0 = *(const f32x4*)ap;
        f32x4 a1 = *(const f32x4*)(ap + 4);
        bf16x8 a;
#pragma unroll
        for (int j = 0; j < 4; ++j) { a[j] = f2bf(a0[j]); a[4 + j] = f2bf(a1[j]); }
#pragma unroll
        for (int ot = 0; ot < 4; ++ot) {
            int o = o0 + ot * 16 + col;
            bf16x8 b = *(const bf16x8*)(PT + (size_t)o * NN + k);
            acc[ot] = __builtin_amdgcn_mfma_f32_16x16x32_bf16(a, b, acc[ot], 0, 0, 0);
        }
    }

    __shared__ float red[4][16][65];
#pragma unroll
    for (int ot = 0; ot < 4; ++ot)
#pragma unroll
        for (int r = 0; r < 4; ++r)
            red[wave][quad * 4 + r][ot * 16 + col] = acc[ot][r];
    __syncthreads();

#pragma unroll
    for (int i = tid; i < 16 * 64; i += 256) {
        int rr = i >> 6;
        int cc = i & 63;
        float v = red[0][rr][cc] + red[1][rr][cc] + red[2][rr][cc] + red[3][rr][cc];
        size_t idx = (size_t)(n0 + rr) * OUT_CH + o0 + cc;
        out[idx] = v + R[idx] + bias[o0 + cc];
    }
}

// ---------------------------------------------------------------------------
// Kernel B v9 (heavy): per node n (ONE block per n, plain += epilogue),
//   G[b]  = sum_m adj[n,m] * relu( sum_e edge_adj[e,n,m] * L1[e,b] )
//   out[n,o] += sum_{b<127} G[b]*L2[b,o]            (base pre-written by adjp)
//
// v8 post-mortem: launch_bounds(256,6) -> 85-VGPR budget, allocator
// undershot to 40 and spilled 203 MB; breadth never tested. v9 is the CLEAN
// breadth test vs v7 (238 us, 3 blocks/CU, edge ~70 us @ 1.9 TB/s):
//   - chunk 128 m -> LDS 26 KB (admits 6 blocks/CU)
//   - f32x2 staging (16 VGPR/bank) -> ~70 live regs
//   - __launch_bounds__(256,5): budget 102 >> 70, 5 blocks/CU, 20 waves/CU
//   - 8-chunk fully-unrolled 2-deep schedule, nt loads, rotation (n+c)&7
// Geometry: wave stages its 8 e-planes (f32x2 = 512 B/plane/instr), LDS
// transposed [m][40 shorts]; b-split waves own b-tiles {2w,2w+1}.
// MFMA 16x16x32: A=L1^T const frags; B=ds_read_b128 [m][e]; D row=quad*4+r.
// ---------------------------------------------------------------------------
__global__ void __launch_bounds__(256, 5)
edge_out_kernel(const float* __restrict__ edge_adj,
                const float* __restrict__ adj,
                const float* __restrict__ L1,
                const float* __restrict__ L2,
                float* __restrict__ out) {
    int n = blockIdx.x;
    int tid = threadIdx.x;
    int wave = tid >> 6;
    int lane = tid & 63;
    int quad = lane >> 4;
    int col  = lane & 15;

    // double-buffered transposed chunk: [128 m][40 shorts] = 10 KB each
    __shared__ __attribute__((aligned(16))) short ea_lds[2][128 * 40];  // 20 KB
    __shared__ float adj_lds[NN];                                       // 4 KB
    __shared__ float gs[OUT_CH];
    __shared__ float part[2][OUT_CH];

    // stage the adj row once (coalesced, 4 KB)
    *(f32x4*)&adj_lds[tid * 4] = *(const f32x4*)(adj + (size_t)n * NN + tid * 4);

    // A fragments: this wave's two b-tiles of L1^T [b][e=quad*8+j]
    bf16x8 a_frag0, a_frag1;
#pragma unroll
    for (int j = 0; j < 8; ++j) {
        int e = quad * 8 + j;
        int b0 = (wave * 2 + 0) * 16 + col;
        int b1 = (wave * 2 + 1) * 16 + col;
        a_frag0[j] = f2bf((b0 < OUT_CH - 1) ? L1[e * (OUT_CH - 1) + b0] : 0.0f);
        a_frag1[j] = f2bf((b1 < OUT_CH - 1) ? L1[e * (OUT_CH - 1) + b1] : 0.0f);
    }

    float g0[4] = {0.f, 0.f, 0.f, 0.f};
    float g1[4] = {0.f, 0.f, 0.f, 0.f};

    // staging base: this wave's 8 e-planes, this n's row, lane covers 2 m
    const float* ea_b = edge_adj + (size_t)(wave * 8) * NNSQ + (size_t)n * NN + lane * 2;

    f32x2 stA0, stA1, stA2, stA3, stA4, stA5, stA6, stA7;   // bank A (16 VGPR)
    f32x2 stB0, stB1, stB2, stB3, stB4, stB5, stB6, stB7;   // bank B (16 VGPR)

#define NTLD(P) __builtin_nontemporal_load((const f32x2*)(P))
#define ISSUE_A(AC) { \
        const float* p_ = ea_b + (AC) * 128; \
        stA0 = NTLD(p_ + 0 * NNSQ); stA1 = NTLD(p_ + 1 * NNSQ); \
        stA2 = NTLD(p_ + 2 * NNSQ); stA3 = NTLD(p_ + 3 * NNSQ); \
        stA4 = NTLD(p_ + 4 * NNSQ); stA5 = NTLD(p_ + 5 * NNSQ); \
        stA6 = NTLD(p_ + 6 * NNSQ); stA7 = NTLD(p_ + 7 * NNSQ); }
#define ISSUE_B(AC) { \
        const float* p_ = ea_b + (AC) * 128; \
        stB0 = NTLD(p_ + 0 * NNSQ); stB1 = NTLD(p_ + 1 * NNSQ); \
        stB2 = NTLD(p_ + 2 * NNSQ); stB3 = NTLD(p_ + 3 * NNSQ); \
        stB4 = NTLD(p_ + 4 * NNSQ); stB5 = NTLD(p_ + 5 * NNSQ); \
        stB6 = NTLD(p_ + 6 * NNSQ); stB7 = NTLD(p_ + 7 * NNSQ); }
// lane holds 8e x 2m; write 2 rows of 8 bf16 (16 B) = 2x ds_write_b128
#define CONVERT_A(BUF) { \
        _Pragma("unroll") for (int k = 0; k < 2; ++k) { \
            bf16x8 pk_; \
            pk_[0] = f2bf(stA0[k]); pk_[1] = f2bf(stA1[k]); \
            pk_[2] = f2bf(stA2[k]); pk_[3] = f2bf(stA3[k]); \
            pk_[4] = f2bf(stA4[k]); pk_[5] = f2bf(stA5[k]); \
            pk_[6] = f2bf(stA6[k]); pk_[7] = f2bf(stA7[k]); \
            *(bf16x8*)((BUF) + (lane * 2 + k) * 40 + wave * 8) = pk_; } }
#define CONVERT_B(BUF) { \
        _Pragma("unroll") for (int k = 0; k < 2; ++k) { \
            bf16x8 pk_; \
            pk_[0] = f2bf(stB0[k]); pk_[1] = f2bf(stB1[k]); \
            pk_[2] = f2bf(stB2[k]); pk_[3] = f2bf(stB3[k]); \
            pk_[4] = f2bf(stB4[k]); pk_[5] = f2bf(stB5[k]); \
            pk_[6] = f2bf(stB6[k]); pk_[7] = f2bf(stB7[k]); \
            *(bf16x8*)((BUF) + (lane * 2 + k) * 40 + wave * 8) = pk_; } }
#define COMPUTE(BUF, AC) { \
        _Pragma("unroll") for (int st = 0; st < 8; ++st) { \
            int mrow = st * 16 + col; \
            float adjv = adj_lds[(AC) * 128 + mrow]; \
            bf16x8 bfv = *(const bf16x8*)((BUF) + mrow * 40 + quad * 8); \
            f32x4 d0 = __builtin_amdgcn_mfma_f32_16x16x32_bf16( \
                a_frag0, bfv, (f32x4){0.f, 0.f, 0.f, 0.f}, 0, 0, 0); \
            f32x4 d1 = __builtin_amdgcn_mfma_f32_16x16x32_bf16( \
                a_frag1, bfv, (f32x4){0.f, 0.f, 0.f, 0.f}, 0, 0, 0); \
            _Pragma("unroll") for (int r = 0; r < 4; ++r) { \
                g0[r] += fmaxf(d0[r], 0.0f) * adjv; \
                g1[r] += fmaxf(d1[r], 0.0f) * adjv; } } }
#define CR(C) ((n + (C)) & 7)

    short* buf0 = &ea_lds[0][0];
    short* buf1 = &ea_lds[1][0];

    // fully-unrolled 8-chunk, 2-deep schedule (all register indices static)
    ISSUE_A(CR(0)); ISSUE_B(CR(1));
    CONVERT_A(buf0);
    __syncthreads();

    ISSUE_A(CR(2)); COMPUTE(buf0, CR(0)); CONVERT_B(buf1); __syncthreads();
    ISSUE_B(CR(3)); COMPUTE(buf1, CR(1)); CONVERT_A(buf0); __syncthreads();
    ISSUE_A(CR(4)); COMPUTE(buf0, CR(2)); CONVERT_B(buf1); __syncthreads();
    ISSUE_B(CR(5)); COMPUTE(buf1, CR(3)); CONVERT_A(buf0); __syncthreads();
    ISSUE_A(CR(6)); COMPUTE(buf0, CR(4)); CONVERT_B(buf1); __syncthreads();
    ISSUE_B(CR(7)); COMPUTE(buf1, CR(5)); CONVERT_A(buf0); __syncthreads();
    COMPUTE(buf0, CR(6)); CONVERT_B(buf1); __syncthreads();
    COMPUTE(buf1, CR(7));

#undef NTLD
#undef ISSUE_A
#undef ISSUE_B
#undef CONVERT_A
#undef CONVERT_B
#undef COMPUTE
#undef CR

    // reduce over the 16 column-lanes (sum over m within subtile columns)
#pragma unroll
    for (int r = 0; r < 4; ++r) {
        float v0 = g0[r], v1 = g1[r];
        v0 += __shfl_xor(v0, 1); v1 += __shfl_xor(v1, 1);
        v0 += __shfl_xor(v0, 2); v1 += __shfl_xor(v1, 2);
        v0 += __shfl_xor(v0, 4); v1 += __shfl_xor(v1, 4);
        v0 += __shfl_xor(v0, 8); v1 += __shfl_xor(v1, 8);
        g0[r] = v0; g1[r] = v1;
    }

    // each b owned by exactly one wave -> write gs directly
    if (col == 0) {
#pragma unroll
        for (int r = 0; r < 4; ++r) {
            gs[(wave * 2 + 0) * 16 + quad * 4 + r] = g0[r];
            gs[(wave * 2 + 1) * 16 + quad * 4 + r] = g1[r];
        }
    }
    __syncthreads();

    // epilogue: out[n,o] += sum_{b<127} gs[b]*L2[b,o]   (plain rmw, single writer)
    int o = tid & 127;
    int hf = tid >> 7;
    float acc = 0.f;
    int blo = hf * 64, bhi = hf ? 127 : 64;
#pragma unroll 8
    for (int b = blo; b < bhi; ++b)
        acc += gs[b] * L2[b * OUT_CH + o];   // gs[b] is an LDS broadcast (free)
    part[hf][o] = acc;
    __syncthreads();
    if (tid < 128) {
        size_t idx = (size_t)n * OUT_CH + tid;
        out[idx] += part[0][tid] + part[1][tid];
    }
}

extern "C" void kernel_launch(void* const* d_in, const int* in_sizes, int n_in,
                              void* d_out, int out_size, void* d_ws, size_t ws_size,
                              hipStream_t stream) {
    const float* node_mat    = (const float*)d_in[0];
    const float* adj         = (const float*)d_in[1];
    const float* edge_adj    = (const float*)d_in[2];
    const float* node_weight = (const float*)d_in[3];
    const float* edge_lay_1  = (const float*)d_in[4];
    const float* edge_lay_2  = (const float*)d_in[5];
    const float* root        = (const float*)d_in[6];
    const float* bias        = (const float*)d_in[7];
    float* out = (float*)d_out;

    short* PT = (short*)d_ws;                       // 128*1024 bf16 = 256 KB
    float* R  = (float*)((char*)d_ws + OUT_CH * NN * sizeof(short));  // 512 KB

    node_gemm_kernel<<<NN / 2, 256, 0, stream>>>(node_mat, node_weight, root, PT, R);
    adjp_kernel<<<128, 256, 0, stream>>>(adj, PT, R, bias, out);   // writes base
    edge_out_kernel<<<NN, 256, 0, stream>>>(edge_adj, adj, edge_lay_1,
                                            edge_lay_2, out);      // plain +=
}